// Round 4
// baseline (727.549 us; speedup 1.0000x reference)
//
#include <hip/hip_runtime.h>

#define B_   8192
#define K_   5
#define D_   128
#define QD_  129
#define KD_  1285
#define SQ_  132      // padded fp32 row stride
#define BK_  40960    // B_*K_
#define QPAD 160      // bf16 k-dim padding (5 x 32)
#define VPAD 144      // bf16 out-dim padding (9 x 16)
#define KDP  1312     // KD_ padded to 41*32

typedef unsigned short u16;
typedef unsigned int   u32;
typedef __attribute__((ext_vector_type(8))) short bf8_t;
typedef __attribute__((ext_vector_type(4))) float f4_t;

#define MFMA16(a, b, c) __builtin_amdgcn_mfma_f32_16x16x32_bf16(a, b, c, 0, 0, 0)

__device__ __forceinline__ u16 f2bf(float x) {
  u32 u = __float_as_uint(x);
  u = (u + 0x7fffu + ((u >> 16) & 1u)) >> 16;
  return (u16)u;
}
__device__ __forceinline__ u32 pack2(float a, float b) {
  return (u32)f2bf(a) | ((u32)f2bf(b) << 16);
}
// LDS layout: row stride 32 u16, 8-u16 sub-blocks XOR-swizzled by row -> max
// 2-way bank aliasing (free) on 16B-aligned ds ops.
__device__ __forceinline__ int swz8(int row, int seg) {
  return (row << 5) + (((seg ^ (row >> 1)) & 3) << 3);
}
#define PIPE_BARRIER() do { \
    asm volatile("s_waitcnt lgkmcnt(0)" ::: "memory"); \
    __builtin_amdgcn_s_barrier(); \
    asm volatile("" ::: "memory"); \
  } while (0)

// ---------------------------------------------------------------------------
// One-time weight conversion fp32 -> bf16 with zero padding.
//   wkv [288][1312] @0        rows 0-128 Wk, 129-257 Wv
//   wq  [144][160]  @377856
//   wo  [144][160]  @400896
//   w1  [144][288]  @423936
//   w2  [144][128]  @465408   (end 483840)
// ---------------------------------------------------------------------------
__global__ __launch_bounds__(256) void convw_k(
    const float* __restrict__ Wq, const float* __restrict__ Wk,
    const float* __restrict__ Wv, const float* __restrict__ Wo,
    const float* __restrict__ W1, const float* __restrict__ W2,
    u16* __restrict__ wb)
{
  int idx = blockIdx.x * 256 + threadIdx.x;
  if (idx < 377856) {
    int r = idx / KDP, c = idx - r * KDP;
    float v = 0.f;
    if (c < KD_) {
      if (r < 129) v = Wk[r * KD_ + c];
      else if (r < 258) v = Wv[(r - 129) * KD_ + c];
    }
    wb[idx] = f2bf(v);
    return;
  }
  int i2 = idx - 377856;
  if (i2 < 23040) {
    int r = i2 / 160, c = i2 - r * 160;
    wb[idx] = f2bf((r < 129 && c < 129) ? Wq[r * 129 + c] : 0.f);
    return;
  }
  i2 -= 23040;
  if (i2 < 23040) {
    int r = i2 / 160, c = i2 - r * 160;
    wb[idx] = f2bf((r < 129 && c < 129) ? Wo[r * 129 + c] : 0.f);
    return;
  }
  i2 -= 23040;
  if (i2 < 41472) {
    int r = i2 / 288, c = i2 - r * 288;
    wb[idx] = f2bf((r < 128 && c < 257) ? W1[r * 257 + c] : 0.f);
    return;
  }
  i2 -= 41472;
  if (i2 < 18432) {
    int r = i2 / 128, c = i2 - r * 128;
    wb[idx] = f2bf(r < 128 ? W2[r * 128 + c] : 0.f);
  }
}

// ---------------------------------------------------------------------------
// Dual KV projection: [kp;vp] = gather(nf) @ Wkv^T + [bk;bv]
// BM=64, BN=288, 256 thr, waves 2Mx2N (wave: 32 rows x 144 cols).
// Double-buffered LDS, issue-early reg staging, one raw barrier per k-step.
// ---------------------------------------------------------------------------
template<int OM0, int OM1>
__global__ __launch_bounds__(256) void kvmm_k(
    const float* __restrict__ emb, const float* __restrict__ ef,
    const float* __restrict__ td, const u16* __restrict__ Wkv,
    const float* __restrict__ b0, void* __restrict__ out0, int ost0,
    const float* __restrict__ b1, void* __restrict__ out1, int ost1)
{
  __shared__ u16 As[2][64 * 32];
  __shared__ u16 Ws[2][288 * 32];
  const int t = threadIdx.x;
  const int n0 = blockIdx.x * 64;
  const int lane = t & 63, w = t >> 6;
  const int lrow = lane & 15, lk = lane >> 4;
  const int wr = w & 1, wc = w >> 1;
  const int cp = t & 15, rbase = t >> 4;

  f4_t acc0[9], acc1[9];
#pragma unroll
  for (int ct = 0; ct < 9; ++ct) {
    acc0[ct] = (f4_t){0.f, 0.f, 0.f, 0.f};
    acc1[ct] = (f4_t){0.f, 0.f, 0.f, 0.f};
  }

  float aA[8];
  uint4 aW[5];

  auto issueA = [&](int kst) {
    const int c = kst * 32 + cp * 2;
    const int j0 = c / 257,       r0v = c - j0 * 257;
    const int j1 = (c + 1) / 257, r1v = (c + 1) - j1 * 257;
#pragma unroll
    for (int ri = 0; ri < 4; ++ri) {
      const int n = n0 + rbase + ri * 16;
      float f0 = 0.f, f1 = 0.f;
      if (j0 < 5) {
        int base = (n * 5 + j0) << 7;
        f0 = (r0v < 128) ? emb[base + r0v]
           : (r0v < 256) ? ef[base + r0v - 128] : td[n * 5 + j0];
      }
      if (j1 < 5) {
        int base = (n * 5 + j1) << 7;
        f1 = (r1v < 128) ? emb[base + r1v]
           : (r1v < 256) ? ef[base + r1v - 128] : td[n * 5 + j1];
      }
      aA[ri * 2] = f0; aA[ri * 2 + 1] = f1;
    }
  };
  auto issueW = [&](int kst) {
    const int c0 = kst * 32;
#pragma unroll
    for (int i = 0; i < 4; ++i) {
      int e = t + i * 256, row = e >> 2, seg = e & 3;
      aW[i] = *(const uint4*)&Wkv[(size_t)row * KDP + c0 + seg * 8];
    }
    if (t < 128) {
      int e = 1024 + t, row = e >> 2, seg = e & 3;
      aW[4] = *(const uint4*)&Wkv[(size_t)row * KDP + c0 + seg * 8];
    }
  };
  auto writeT = [&](int cur) {
#pragma unroll
    for (int ri = 0; ri < 4; ++ri) {
      const int row = rbase + ri * 16;
      *(u32*)&As[cur][swz8(row, cp >> 2) + ((cp & 3) << 1)] =
          pack2(aA[ri * 2], aA[ri * 2 + 1]);
    }
#pragma unroll
    for (int i = 0; i < 4; ++i) {
      int e = t + i * 256, row = e >> 2, seg = e & 3;
      *(uint4*)&Ws[cur][swz8(row, seg)] = aW[i];
    }
    if (t < 128) {
      int e = 1024 + t, row = e >> 2, seg = e & 3;
      *(uint4*)&Ws[cur][swz8(row, seg)] = aW[4];
    }
  };

  issueA(0); issueW(0);
  int cur = 0;
  for (int kst = 0; kst < 41; ++kst) {
    writeT(cur);
    if (kst < 40) { issueA(kst + 1); issueW(kst + 1); }
    PIPE_BARRIER();
    bf8_t af0 = *(const bf8_t*)&As[cur][swz8(wr * 32 + lrow, lk)];
    bf8_t af1 = *(const bf8_t*)&As[cur][swz8(wr * 32 + 16 + lrow, lk)];
#pragma unroll
    for (int ct = 0; ct < 9; ++ct) {
      bf8_t bf = *(const bf8_t*)&Ws[cur][swz8(wc * 144 + ct * 16 + lrow, lk)];
      acc0[ct] = MFMA16(af0, bf, acc0[ct]);
      acc1[ct] = MFMA16(af1, bf, acc1[ct]);
    }
    cur ^= 1;
  }

#pragma unroll
  for (int ct = 0; ct < 9; ++ct) {
    const int col = wc * 144 + ct * 16 + lrow;
#pragma unroll
    for (int rf = 0; rf < 2; ++rf) {
#pragma unroll
      for (int r = 0; r < 4; ++r) {
        const int n = n0 + wr * 32 + rf * 16 + lk * 4 + r;
        float v = (rf == 0) ? acc0[ct][r] : acc1[ct][r];
        if (col < 129) {
          v += b0[col];
          if (OM0 == 0)      ((float*)out0)[(size_t)n * ost0 + col] = v;
          else if (OM0 == 1) ((u16*)out0)[(size_t)n * ost0 + col] = f2bf(v);
          else               ((u16*)out0)[(size_t)col * ost0 + n] = f2bf(v);
        } else if (col < 258) {
          int o = col - 129;
          v += b1[o];
          if (OM1 == 0)      ((float*)out1)[(size_t)n * ost1 + o] = v;
          else if (OM1 == 1) ((u16*)out1)[(size_t)n * ost1 + o] = f2bf(v);
          else               ((u16*)out1)[(size_t)o * ost1 + n] = f2bf(v);
        }
      }
    }
  }
}

// ---------------------------------------------------------------------------
// Generic bf16 MFMA GEMM: out[n][o] = op((A[n]@Wb[o] + bias[o]) * scale)
// BM=64, N<=144, 256 thr, 4 waves x (16 rows x 144 cols). K = nK*32.
// GMB=0: A bf16 row-major (stride ast). GMB=1: A=[emb f32 |td|0] q-input.
// Same double-buffered pipeline as kvmm_k.
// ---------------------------------------------------------------------------
template<int GMB, bool RELU, int OM>
__global__ __launch_bounds__(256) void mmb_k(
    int nK, const void* __restrict__ A, int ast, const float* __restrict__ td,
    const u16* __restrict__ Wb, const float* __restrict__ bias, float scale,
    void* __restrict__ out, int ost, int N)
{
  __shared__ u16 As[2][64 * 32];
  __shared__ u16 Ws[2][144 * 32];
  const int t = threadIdx.x;
  const int n0 = blockIdx.x * 64;
  const int lane = t & 63, w = t >> 6;
  const int lrow = lane & 15, lk = lane >> 4;
  const int cp = t & 15, rbase = t >> 4;
  const int Kw = nK * 32;

  f4_t acc[9];
#pragma unroll
  for (int ct = 0; ct < 9; ++ct) acc[ct] = (f4_t){0.f, 0.f, 0.f, 0.f};

  uint4 aA4; float aA[8];
  uint4 aW[3];

  auto issueA = [&](int kst) {
    if (GMB == 0) {
      int row = t >> 2, seg = t & 3;
      aA4 = *(const uint4*)((const u16*)A + (size_t)(n0 + row) * ast + kst * 32 + seg * 8);
    } else {
      const int c = kst * 32 + cp * 2;
#pragma unroll
      for (int ri = 0; ri < 4; ++ri) {
        const int n = n0 + rbase + ri * 16;
        float f0 = 0.f, f1 = 0.f;
        if (c < 128)       f0 = ((const float*)A)[(n << 7) + c];
        else if (c == 128) f0 = td ? td[n] : 0.f;
        if (c + 1 < 128)       f1 = ((const float*)A)[(n << 7) + c + 1];
        else if (c + 1 == 128) f1 = td ? td[n] : 0.f;
        aA[ri * 2] = f0; aA[ri * 2 + 1] = f1;
      }
    }
  };
  auto issueW = [&](int kst) {
    const int c0 = kst * 32;
#pragma unroll
    for (int i = 0; i < 2; ++i) {
      int e = t + i * 256, row = e >> 2, seg = e & 3;
      aW[i] = *(const uint4*)&Wb[(size_t)row * Kw + c0 + seg * 8];
    }
    if (t < 64) {
      int e = 512 + t, row = e >> 2, seg = e & 3;
      aW[2] = *(const uint4*)&Wb[(size_t)row * Kw + c0 + seg * 8];
    }
  };
  auto writeT = [&](int cur) {
    if (GMB == 0) {
      int row = t >> 2, seg = t & 3;
      *(uint4*)&As[cur][swz8(row, seg)] = aA4;
    } else {
#pragma unroll
      for (int ri = 0; ri < 4; ++ri) {
        const int row = rbase + ri * 16;
        *(u32*)&As[cur][swz8(row, cp >> 2) + ((cp & 3) << 1)] =
            pack2(aA[ri * 2], aA[ri * 2 + 1]);
      }
    }
#pragma unroll
    for (int i = 0; i < 2; ++i) {
      int e = t + i * 256, row = e >> 2, seg = e & 3;
      *(uint4*)&Ws[cur][swz8(row, seg)] = aW[i];
    }
    if (t < 64) {
      int e = 512 + t, row = e >> 2, seg = e & 3;
      *(uint4*)&Ws[cur][swz8(row, seg)] = aW[2];
    }
  };

  issueA(0); issueW(0);
  int cur = 0;
  for (int kst = 0; kst < nK; ++kst) {
    writeT(cur);
    if (kst < nK - 1) { issueA(kst + 1); issueW(kst + 1); }
    PIPE_BARRIER();
    bf8_t af = *(const bf8_t*)&As[cur][swz8(w * 16 + lrow, lk)];
#pragma unroll
    for (int ct = 0; ct < 9; ++ct) {
      bf8_t bf = *(const bf8_t*)&Ws[cur][swz8(ct * 16 + lrow, lk)];
      acc[ct] = MFMA16(af, bf, acc[ct]);
    }
    cur ^= 1;
  }

#pragma unroll
  for (int ct = 0; ct < 9; ++ct) {
    const int col = ct * 16 + lrow;
    if (col < N) {
      const float bb = bias[col];
#pragma unroll
      for (int r = 0; r < 4; ++r) {
        const int n = n0 + w * 16 + lk * 4 + r;
        float v = (acc[ct][r] + bb) * scale;
        if (RELU) v = fmaxf(v, 0.f);
        if (OM == 0) ((float*)out)[(size_t)n * ost + col] = v;
        else         ((u16*)out)[(size_t)n * ost + col] = f2bf(v);
      }
    }
  }
}

// ---------------------------------------------------------------------------
// emb pack: f32 [rows][128] -> bf16 into dst cols 129..256 (stride 288)
// ---------------------------------------------------------------------------
__global__ __launch_bounds__(256) void embpack_k(
    const float* __restrict__ src, u16* __restrict__ dst, int rows)
{
  int idx = blockIdx.x * 256 + threadIdx.x;
  if (idx >= rows * 128) return;
  int n = idx >> 7, c = idx & 127;
  dst[(size_t)n * 288 + 129 + c] = f2bf(src[idx]);
}

// ---------------------------------------------------------------------------
// i=0 attention: per batch b, 5 queries x 5 keys, dim 129.
// ---------------------------------------------------------------------------
__global__ __launch_bounds__(256) void attn0_k(
    const float* __restrict__ qp, const float* __restrict__ kp,
    const float* __restrict__ vp, u16* __restrict__ o0b)
{
  __shared__ float qs[4][5][SQ_], ks[4][5][SQ_], vs[4][5][SQ_];
  __shared__ float ps[4][5][8];
  const int t = threadIdx.x;
  const int bbase = blockIdx.x * 4;
  for (int idx = t; idx < 4 * 5 * SQ_; idx += 256) {
    int bl = idx / (5 * SQ_);
    int rem = idx - bl * 5 * SQ_;
    int row = rem / SQ_;
    int d = rem - row * SQ_;
    int n = (bbase + bl) * 5 + row;
    float qv = 0.f, kv = 0.f, vv = 0.f;
    if (d < QD_) { qv = qp[n * SQ_ + d]; kv = kp[n * SQ_ + d]; vv = vp[n * SQ_ + d]; }
    qs[bl][row][d] = qv; ks[bl][row][d] = kv; vs[bl][row][d] = vv;
  }
  __syncthreads();
  const int w = t >> 6, lane = t & 63;
  if (lane < 25) {
    int qq = lane / 5, kk = lane - (lane / 5) * 5;
    float s = 0.f;
    for (int c = 0; c < QD_; ++c) s += qs[w][qq][c] * ks[w][kk][c];
    ps[w][qq][kk] = s;
  }
  __syncthreads();
  if (lane < 5) {
    float m = -1e30f;
#pragma unroll
    for (int k = 0; k < 5; ++k) m = fmaxf(m, ps[w][lane][k]);
    float l = 0.f; float e[5];
#pragma unroll
    for (int k = 0; k < 5; ++k) { e[k] = __expf(ps[w][lane][k] - m); l += e[k]; }
    float inv = 1.f / l;
#pragma unroll
    for (int k = 0; k < 5; ++k) ps[w][lane][k] = e[k] * inv;
  }
  __syncthreads();
  for (int d = lane; d < 160; d += 64) {
#pragma unroll
    for (int qq = 0; qq < 5; ++qq) {
      float o = 0.f;
      if (d < QD_) {
#pragma unroll
        for (int k = 0; k < 5; ++k) o += ps[w][qq][k] * vs[w][k][d];
      }
      o0b[(size_t)((bbase + w) * 5 + qq) * 160 + d] = f2bf(o);
    }
  }
}

// ---------------------------------------------------------------------------
// i=1 MFMA flash attention (unchanged).
// ---------------------------------------------------------------------------
#define KSS 168
#define VSS 72
#define PSS 72
#define NSPLIT 4
__global__ __launch_bounds__(256) void flashm_k(
    const u16* __restrict__ qp, const u16* __restrict__ kp,
    const u16* __restrict__ vpT, float* __restrict__ oacc,
    float* __restrict__ marr, float* __restrict__ larr)
{
  __shared__ u16 ks[64 * KSS];
  __shared__ u16 vsT[VPAD * VSS];
  __shared__ u16 ps[64 * PSS];
  const int t = threadIdx.x;
  const int split = blockIdx.x & (NSPLIT - 1);
  const int q0 = (blockIdx.x >> 2) * 64;
  const int w = t >> 6, lane = t & 63;
  const int lrow = lane & 15, lk = lane >> 4;

  bf8_t qf[5];
  {
    const u16* qrow = qp + (size_t)(q0 + w * 16 + lrow) * QPAD;
#pragma unroll
    for (int kst = 0; kst < 5; ++kst)
      qf[kst] = *(const bf8_t*)(qrow + kst * 32 + lk * 8);
  }

  f4_t acc[9];
#pragma unroll
  for (int ct = 0; ct < 9; ++ct) acc[ct] = (f4_t){0.f, 0.f, 0.f, 0.f};
  float m_[4] = {-1e30f, -1e30f, -1e30f, -1e30f};
  float l_[4] = {0.f, 0.f, 0.f, 0.f};

  const int kbase = split * (B_ / NSPLIT);
  for (int tile = 0; tile < (B_ / NSPLIT) / 64; ++tile) {
    const int k0 = kbase + tile * 64;
    __syncthreads();
    for (int e = t; e < 64 * 20; e += 256) {
      int r = e / 20, c = e - r * 20;
      *(uint4*)&ks[r * KSS + c * 8] = *(const uint4*)(kp + (size_t)(k0 + r) * QPAD + c * 8);
    }
    for (int e = t; e < VPAD * 8; e += 256) {
      int r = e >> 3, c = e & 7;
      *(uint4*)&vsT[r * VSS + c * 8] = *(const uint4*)(vpT + (size_t)r * B_ + k0 + c * 8);
    }
    __syncthreads();

    f4_t s[4];
#pragma unroll
    for (int ct = 0; ct < 4; ++ct) s[ct] = (f4_t){0.f, 0.f, 0.f, 0.f};
#pragma unroll
    for (int kst = 0; kst < 5; ++kst) {
#pragma unroll
      for (int ct = 0; ct < 4; ++ct) {
        bf8_t b = *(const bf8_t*)&ks[(ct * 16 + lrow) * KSS + kst * 32 + lk * 8];
        s[ct] = MFMA16(qf[kst], b, s[ct]);
      }
    }

    float pm[4];
#pragma unroll
    for (int r = 0; r < 4; ++r) {
      pm[r] = fmaxf(fmaxf(s[0][r], s[1][r]), fmaxf(s[2][r], s[3][r]));
#pragma unroll
      for (int mk = 1; mk <= 8; mk <<= 1) pm[r] = fmaxf(pm[r], __shfl_xor(pm[r], mk));
    }
    float cf[4], rs[4];
#pragma unroll
    for (int r = 0; r < 4; ++r) {
      float mn = fmaxf(m_[r], pm[r]);
      cf[r] = __expf(m_[r] - mn);
      m_[r] = mn;
      rs[r] = 0.f;
    }
#pragma unroll
    for (int ct = 0; ct < 4; ++ct) {
#pragma unroll
      for (int r = 0; r < 4; ++r) {
        float p = __expf(s[ct][r] - m_[r]);
        ps[(w * 16 + lk * 4 + r) * PSS + ct * 16 + lrow] = f2bf(p);
        rs[r] += p;
      }
    }
#pragma unroll
    for (int r = 0; r < 4; ++r) {
#pragma unroll
      for (int mk = 1; mk <= 8; mk <<= 1) rs[r] += __shfl_xor(rs[r], mk);
      l_[r] = l_[r] * cf[r] + rs[r];
    }
#pragma unroll
    for (int ct = 0; ct < 9; ++ct) {
#pragma unroll
      for (int r = 0; r < 4; ++r) acc[ct][r] *= cf[r];
    }
    __syncthreads();

#pragma unroll
    for (int kst = 0; kst < 2; ++kst) {
      bf8_t a = *(const bf8_t*)&ps[(w * 16 + lrow) * PSS + kst * 32 + lk * 8];
#pragma unroll
      for (int ct = 0; ct < 9; ++ct) {
        bf8_t b = *(const bf8_t*)&vsT[(ct * 16 + lrow) * VSS + kst * 32 + lk * 8];
        acc[ct] = MFMA16(a, b, acc[ct]);
      }
    }
  }

#pragma unroll
  for (int ct = 0; ct < 9; ++ct) {
    const int col = ct * 16 + lrow;
    if (col < SQ_) {
#pragma unroll
      for (int r = 0; r < 4; ++r)
        oacc[((size_t)split * B_ + q0 + w * 16 + lk * 4 + r) * SQ_ + col] = acc[ct][r];
    }
  }
  if (lrow == 0) {
#pragma unroll
    for (int r = 0; r < 4; ++r) {
      size_t i = (size_t)split * B_ + q0 + w * 16 + lk * 4 + r;
      marr[i] = m_[r];
      larr[i] = l_[r];
    }
  }
}

// ---------------------------------------------------------------------------
// combine splits -> o1b bf16 [8192][160] (pads zeroed)
// ---------------------------------------------------------------------------
__global__ __launch_bounds__(256) void combine_k(
    const float* __restrict__ oacc, const float* __restrict__ marr,
    const float* __restrict__ larr, u16* __restrict__ o1b)
{
  int idx = blockIdx.x * 256 + threadIdx.x;
  if (idx >= B_ * 160) return;
  int n = idx / 160, d = idx - n * 160;
  float v = 0.f;
  if (d < QD_) {
    float m = -1e30f;
#pragma unroll
    for (int s = 0; s < NSPLIT; ++s) m = fmaxf(m, marr[s * B_ + n]);
    float l = 0.f, o = 0.f;
#pragma unroll
    for (int s = 0; s < NSPLIT; ++s) {
      float e = __expf(marr[s * B_ + n] - m);
      l += larr[s * B_ + n] * e;
      o += oacc[((size_t)s * B_ + n) * SQ_ + d] * e;
    }
    v = o / l;
  }
  o1b[idx] = f2bf(v);
}

// ---------------------------------------------------------------------------
extern "C" void kernel_launch(void* const* d_in, const int* in_sizes, int n_in,
                              void* d_out, int out_size, void* d_ws, size_t ws_size,
                              hipStream_t stream)
{
  const float* emb0 = (const float*)d_in[0];
  const float* ef0  = (const float*)d_in[1];
  const float* td0  = (const float*)d_in[2];
  const float* emb1 = (const float*)d_in[3];
  const float* ef1  = (const float*)d_in[4];
  const float* td1  = (const float*)d_in[5];
  const float* emb2 = (const float*)d_in[6];
  const float* Wq = (const float*)d_in[7];  const float* bq = (const float*)d_in[8];
  const float* Wk = (const float*)d_in[9];  const float* bk = (const float*)d_in[10];
  const float* Wv = (const float*)d_in[11]; const float* bv = (const float*)d_in[12];
  const float* Wo = (const float*)d_in[13]; const float* bo = (const float*)d_in[14];
  const float* W1 = (const float*)d_in[15]; const float* b1 = (const float*)d_in[16];
  const float* W2 = (const float*)d_in[17]; const float* b2 = (const float*)d_in[18];
  float* out = (float*)d_out;

  char* ws = (char*)d_ws;
  u16* wb   = (u16*)ws;
  u16* wkv  = wb;
  u16* wq_b = wb + 377856;
  u16* wo_b = wb + 400896;
  u16* w1_b = wb + 423936;
  u16* w2_b = wb + 465408;
  float* kp0 = (float*)(ws + 1048576);    // [40960][132] f32
  float* vp0 = (float*)(ws + 22675456);
  float* qp0 = (float*)(ws + 44302336);
  u16*   o0b = (u16*)(ws + 65929216);     // [40960][160] bf16
  u16*   cat0= (u16*)(ws + 1048576);      // [40960][288] bf16 (overlays kp0/vp0)
  u16*   h0  = (u16*)(ws + 24641536);     // [40960][128] bf16
  u16*   qp1b = (u16*)(ws + 44302336);    // [8192][160]
  u16*   kp1b = (u16*)(ws + 46923776);
  u16*   vp1T = (u16*)(ws + 49545216);    // [144][8192]
  u16*   o1b  = (u16*)(ws + 51904512);    // [8192][160]
  float* marr = (float*)(ws + 54525952);
  float* larr = (float*)(ws + 54657024);
  u16*   cat1 = (u16*)(ws + 54788096);    // [8192][288]
  u16*   h1   = (u16*)(ws + 59506688);    // [8192][128]
  float* oacc = (float*)(ws + 79036416);  // [4][8192][132]

  const float scale = 0.08804509063256238f;  // 1/sqrt(129)

  convw_k<<<1890, 256, 0, stream>>>(Wq, Wk, Wv, Wo, W1, W2, wb);

  // ---- i = 0 -------------------------------------------------------------
  kvmm_k<0, 0><<<BK_ / 64, 256, 0, stream>>>(
      emb0, ef0, td0, wkv, bk, kp0, SQ_, bv, vp0, SQ_);
  mmb_k<1, false, 0><<<BK_ / 64, 256, 0, stream>>>(
      5, emb1, 0, td1, wq_b, bq, scale, qp0, SQ_, QD_);
  attn0_k<<<B_ / 4, 256, 0, stream>>>(qp0, kp0, vp0, o0b);
  hipMemsetAsync(cat0, 0, 23592960, stream);
  embpack_k<<<(BK_ * 128 + 255) / 256, 256, 0, stream>>>(emb1, cat0, BK_);
  mmb_k<0, false, 1><<<BK_ / 64, 256, 0, stream>>>(
      5, o0b, 160, nullptr, wo_b, bo, 1.f, cat0, 288, QD_);
  mmb_k<0, true, 1><<<BK_ / 64, 256, 0, stream>>>(
      9, cat0, 288, nullptr, w1_b, b1, 1.f, h0, 128, 128);
  mmb_k<0, false, 0><<<BK_ / 64, 256, 0, stream>>>(
      4, h0, 128, nullptr, w2_b, b2, 1.f, out, 128, 128);

  // ---- i = 1 -------------------------------------------------------------
  hipMemsetAsync(qp1b, 0, 2621440, stream);
  hipMemsetAsync(kp1b, 0, 2621440, stream);
  hipMemsetAsync(vp1T, 0, 2359296, stream);
  kvmm_k<1, 2><<<B_ / 64, 256, 0, stream>>>(
      emb1, ef1, td1, wkv, bk, kp1b, QPAD, bv, vp1T, B_);
  mmb_k<1, false, 1><<<B_ / 64, 256, 0, stream>>>(
      5, emb2, 0, nullptr, wq_b, bq, scale, qp1b, QPAD, QD_);
  flashm_k<<<(B_ / 64) * NSPLIT, 256, 0, stream>>>(qp1b, kp1b, vp1T, oacc, marr, larr);
  combine_k<<<(B_ * 160 + 255) / 256, 256, 0, stream>>>(oacc, marr, larr, o1b);
  hipMemsetAsync(cat1, 0, 4718592, stream);
  embpack_k<<<(B_ * 128 + 255) / 256, 256, 0, stream>>>(emb2, cat1, B_);
  mmb_k<0, false, 1><<<B_ / 64, 256, 0, stream>>>(
      5, o1b, 160, nullptr, wo_b, bo, 1.f, cat1, 288, QD_);
  mmb_k<0, true, 1><<<B_ / 64, 256, 0, stream>>>(
      9, cat1, 288, nullptr, w1_b, b1, 1.f, h1, 128, 128);
  mmb_k<0, false, 0><<<B_ / 64, 256, 0, stream>>>(
      4, h1, 128, nullptr, w2_b, b2, 1.f, out + (size_t)BK_ * D_, 128, 128);
}

// Round 5
// 540.924 us; speedup vs baseline: 1.3450x; 1.3450x over previous
//
#include <hip/hip_runtime.h>

#define B_   8192
#define K_   5
#define D_   128
#define QD_  129
#define KD_  1285
#define SQ_  132      // padded fp32 row stride
#define BK_  40960    // B_*K_
#define QPAD 160      // bf16 k-dim padding (5 x 32)
#define VPAD 144      // bf16 out-dim padding (9 x 16)
#define KDP  1312     // KD_ padded to 41*32

typedef unsigned short u16;
typedef unsigned int   u32;
typedef __attribute__((ext_vector_type(8))) short bf8_t;
typedef __attribute__((ext_vector_type(4))) float f4_t;
typedef __attribute__((address_space(3))) u32 lds_u32;
typedef __attribute__((address_space(1))) const u32 glob_u32;

#define MFMA16(a, b, c) __builtin_amdgcn_mfma_f32_16x16x32_bf16(a, b, c, 0, 0, 0)

__device__ __forceinline__ u16 f2bf(float x) {
  u32 u = __float_as_uint(x);
  u = (u + 0x7fffu + ((u >> 16) & 1u)) >> 16;
  return (u16)u;
}
__device__ __forceinline__ u32 pack2(float a, float b) {
  return (u32)f2bf(a) | ((u32)f2bf(b) << 16);
}
// LDS layout: row stride 32 u16 (64B), 8-u16 sub-blocks XOR-swizzled by row.
// Slot (row, s) holds global content (row, s ^ ((row>>1)&3)); read with swz8.
__device__ __forceinline__ int swz8(int row, int seg) {
  return (row << 5) + (((seg ^ (row >> 1)) & 3) << 3);
}
// global -> LDS DMA, 16B/lane, 64 lanes = 16 rows x 64B. LDS dest linear
// (wave-uniform base + lane*16); source address carries the swizzle.
__device__ __forceinline__ void gload16(const u16* src, u16* ldsdst) {
  __builtin_amdgcn_global_load_lds((glob_u32*)src, (lds_u32*)ldsdst, 16, 0, 0);
}
#define WAIT_VM0()  asm volatile("s_waitcnt vmcnt(0)" ::: "memory")
#define WAIT_LGKM0() asm volatile("s_waitcnt lgkmcnt(0)" ::: "memory")

// ---------------------------------------------------------------------------
// One-time weight conversion fp32 -> bf16 with zero padding.
//   wkv [288][1312] @0        rows 0-128 Wk, 129-257 Wv
//   wq  [144][160]  @377856
//   wo  [144][160]  @400896
//   w1  [144][288]  @423936
//   w2  [144][128]  @465408   (end 483840)
// ---------------------------------------------------------------------------
__global__ __launch_bounds__(256) void convw_k(
    const float* __restrict__ Wq, const float* __restrict__ Wk,
    const float* __restrict__ Wv, const float* __restrict__ Wo,
    const float* __restrict__ W1, const float* __restrict__ W2,
    u16* __restrict__ wb)
{
  int idx = blockIdx.x * 256 + threadIdx.x;
  if (idx < 377856) {
    int r = idx / KDP, c = idx - r * KDP;
    float v = 0.f;
    if (c < KD_) {
      if (r < 129) v = Wk[r * KD_ + c];
      else if (r < 258) v = Wv[(r - 129) * KD_ + c];
    }
    wb[idx] = f2bf(v);
    return;
  }
  int i2 = idx - 377856;
  if (i2 < 23040) {
    int r = i2 / 160, c = i2 - r * 160;
    wb[idx] = f2bf((r < 129 && c < 129) ? Wq[r * 129 + c] : 0.f);
    return;
  }
  i2 -= 23040;
  if (i2 < 23040) {
    int r = i2 / 160, c = i2 - r * 160;
    wb[idx] = f2bf((r < 129 && c < 129) ? Wo[r * 129 + c] : 0.f);
    return;
  }
  i2 -= 23040;
  if (i2 < 41472) {
    int r = i2 / 288, c = i2 - r * 288;
    wb[idx] = f2bf((r < 128 && c < 257) ? W1[r * 257 + c] : 0.f);
    return;
  }
  i2 -= 41472;
  if (i2 < 18432) {
    int r = i2 / 128, c = i2 - r * 128;
    wb[idx] = f2bf(r < 128 ? W2[r * 128 + c] : 0.f);
  }
}

// ---------------------------------------------------------------------------
// Dual KV projection: [kp;vp] = gather(nf) @ Wkv^T + [bk;bv]
// BM=64, BN=288, 256 thr, waves 2Mx2N (wave: 32 rows x 144 cols).
// W staged via global_load_lds (pre-swizzled source, linear LDS dest);
// A gathered fp32->bf16 through 8 regs. 1 barrier + 1 vmcnt(0) per k-step.
// ---------------------------------------------------------------------------
template<int OM0, int OM1>
__global__ __launch_bounds__(256) void kvmm_k(
    const float* __restrict__ emb, const float* __restrict__ ef,
    const float* __restrict__ td, const u16* __restrict__ Wkv,
    const float* __restrict__ b0, void* __restrict__ out0, int ost0,
    const float* __restrict__ b1, void* __restrict__ out1, int ost1)
{
  __shared__ u16 As[2][64 * 32];
  __shared__ u16 Ws[2][288 * 32];
  const int t = threadIdx.x;
  const int n0 = blockIdx.x * 64;
  const int lane = t & 63, w = t >> 6;
  const int lrow = lane & 15, lk = lane >> 4;
  const int wr = w & 1, wc = w >> 1;
  const int cp = t & 15, rbase = t >> 4;
  const int drow = lane >> 2, dseg = lane & 3;   // DMA lane coords

  f4_t acc0[9], acc1[9];
#pragma unroll
  for (int ct = 0; ct < 9; ++ct) {
    acc0[ct] = (f4_t){0.f, 0.f, 0.f, 0.f};
    acc1[ct] = (f4_t){0.f, 0.f, 0.f, 0.f};
  }

  float aA[8];

  auto issueA = [&](int kst) {
    const int c = kst * 32 + cp * 2;
    const int j0 = c / 257,       r0v = c - j0 * 257;
    const int j1 = (c + 1) / 257, r1v = (c + 1) - j1 * 257;
#pragma unroll
    for (int ri = 0; ri < 4; ++ri) {
      const int n = n0 + rbase + ri * 16;
      float f0 = 0.f, f1 = 0.f;
      if (j0 < 5) {
        int base = (n * 5 + j0) << 7;
        f0 = (r0v < 128) ? emb[base + r0v]
           : (r0v < 256) ? ef[base + r0v - 128] : td[n * 5 + j0];
      }
      if (j1 < 5) {
        int base = (n * 5 + j1) << 7;
        f1 = (r1v < 128) ? emb[base + r1v]
           : (r1v < 256) ? ef[base + r1v - 128] : td[n * 5 + j1];
      }
      aA[ri * 2] = f0; aA[ri * 2 + 1] = f1;
    }
  };
  auto writeA = [&](u16* buf) {
#pragma unroll
    for (int ri = 0; ri < 4; ++ri) {
      const int row = rbase + ri * 16;
      *(u32*)&buf[(row << 5) + ((((cp >> 2) ^ (row >> 1)) & 3) << 3) + ((cp & 3) << 1)] =
          pack2(aA[ri * 2], aA[ri * 2 + 1]);
    }
  };
  auto dmaW = [&](int kst, int b) {
    const int c0 = kst * 32;
#pragma unroll
    for (int si = 0; si < 5; ++si) {
      int s = w + si * 4;
      if (s < 18) {                     // wave-uniform
        int rr = s * 16 + drow;
        int sseg = (dseg ^ (rr >> 1)) & 3;
        gload16(&Wkv[(size_t)rr * KDP + c0 + sseg * 8], &Ws[b][s * 512]);
      }
    }
  };

  // prologue
  issueA(0);
  dmaW(0, 0);
  WAIT_VM0();
  writeA(As[0]);
  issueA(1);
  WAIT_LGKM0();
  __builtin_amdgcn_s_barrier();

  int cur = 0;
  for (int kst = 0; kst < 41; ++kst) {
    if (kst < 40) dmaW(kst + 1, cur ^ 1);
    bf8_t af0 = *(const bf8_t*)&As[cur][swz8(wr * 32 +      lrow, lk)];
    bf8_t af1 = *(const bf8_t*)&As[cur][swz8(wr * 32 + 16 + lrow, lk)];
#pragma unroll
    for (int ct = 0; ct < 9; ++ct) {
      bf8_t bf = *(const bf8_t*)&Ws[cur][swz8(wc * 144 + ct * 16 + lrow, lk)];
      acc0[ct] = MFMA16(af0, bf, acc0[ct]);
      acc1[ct] = MFMA16(af1, bf, acc1[ct]);
    }
    if (kst < 40) {
      WAIT_VM0();                 // A_{kst+1} regs + W_{kst+1} DMA landed
      writeA(As[cur ^ 1]);
      if (kst < 39) issueA(kst + 2);   // stays in flight across barrier
      WAIT_LGKM0();
      __builtin_amdgcn_s_barrier();
    }
    cur ^= 1;
  }

#pragma unroll
  for (int ct = 0; ct < 9; ++ct) {
    const int col = wc * 144 + ct * 16 + lrow;
#pragma unroll
    for (int rf = 0; rf < 2; ++rf) {
#pragma unroll
      for (int r = 0; r < 4; ++r) {
        const int n = n0 + wr * 32 + rf * 16 + lk * 4 + r;
        float v = (rf == 0) ? acc0[ct][r] : acc1[ct][r];
        if (col < 129) {
          v += b0[col];
          if (OM0 == 0)      ((float*)out0)[(size_t)n * ost0 + col] = v;
          else if (OM0 == 1) ((u16*)out0)[(size_t)n * ost0 + col] = f2bf(v);
          else               ((u16*)out0)[(size_t)col * ost0 + n] = f2bf(v);
        } else if (col < 258) {
          int o = col - 129;
          v += b1[o];
          if (OM1 == 0)      ((float*)out1)[(size_t)n * ost1 + o] = v;
          else if (OM1 == 1) ((u16*)out1)[(size_t)n * ost1 + o] = f2bf(v);
          else               ((u16*)out1)[(size_t)o * ost1 + n] = f2bf(v);
        }
      }
    }
  }
}

// ---------------------------------------------------------------------------
// Generic bf16 MFMA GEMM: out[n][o] = op((A[n]@Wb[o] + bias[o]) * scale)
// BM=64, N<=144, 256 thr, 4 waves x (16 rows x 144 cols). K = nK*32.
// GMB=0: A bf16 row-major -> both A and W via global_load_lds DMA.
// GMB=1: A=[emb f32 |td|0] gathered via regs; W via DMA.
// ---------------------------------------------------------------------------
template<int GMB, bool RELU, int OM>
__global__ __launch_bounds__(256) void mmb_k(
    int nK, const void* __restrict__ A, int ast, const float* __restrict__ td,
    const u16* __restrict__ Wb, const float* __restrict__ bias, float scale,
    void* __restrict__ out, int ost, int N)
{
  __shared__ u16 As[2][64 * 32];
  __shared__ u16 Ws[2][144 * 32];
  const int t = threadIdx.x;
  const int n0 = blockIdx.x * 64;
  const int lane = t & 63, w = t >> 6;
  const int lrow = lane & 15, lk = lane >> 4;
  const int cp = t & 15, rbase = t >> 4;
  const int drow = lane >> 2, dseg = lane & 3;
  const int Kw = nK * 32;

  f4_t acc[9];
#pragma unroll
  for (int ct = 0; ct < 9; ++ct) acc[ct] = (f4_t){0.f, 0.f, 0.f, 0.f};

  float aA[8];

  auto issueA = [&](int kst) {        // GMB==1 only
    const int c = kst * 32 + cp * 2;
#pragma unroll
    for (int ri = 0; ri < 4; ++ri) {
      const int n = n0 + rbase + ri * 16;
      float f0 = 0.f, f1 = 0.f;
      if (c < 128)       f0 = ((const float*)A)[(n << 7) + c];
      else if (c == 128) f0 = td ? td[n] : 0.f;
      if (c + 1 < 128)       f1 = ((const float*)A)[(n << 7) + c + 1];
      else if (c + 1 == 128) f1 = td ? td[n] : 0.f;
      aA[ri * 2] = f0; aA[ri * 2 + 1] = f1;
    }
  };
  auto writeA = [&](u16* buf) {
#pragma unroll
    for (int ri = 0; ri < 4; ++ri) {
      const int row = rbase + ri * 16;
      *(u32*)&buf[(row << 5) + ((((cp >> 2) ^ (row >> 1)) & 3) << 3) + ((cp & 3) << 1)] =
          pack2(aA[ri * 2], aA[ri * 2 + 1]);
    }
  };
  auto dmaA = [&](int kst, int b) {   // GMB==0 only: 64 rows, 1 inst/wave
    int rr = w * 16 + drow;
    int sseg = (dseg ^ (rr >> 1)) & 3;
    gload16((const u16*)A + (size_t)(n0 + rr) * ast + kst * 32 + sseg * 8,
            &As[b][w * 512]);
  };
  auto dmaW = [&](int kst, int b) {
    const int c0 = kst * 32;
#pragma unroll
    for (int si = 0; si < 3; ++si) {
      int s = w + si * 4;
      if (s < 9) {                    // wave-uniform
        int rr = s * 16 + drow;
        int sseg = (dseg ^ (rr >> 1)) & 3;
        gload16(&Wb[(size_t)rr * Kw + c0 + sseg * 8], &Ws[b][s * 512]);
      }
    }
  };

  // prologue
  if (GMB == 0) {
    dmaA(0, 0); dmaW(0, 0);
    WAIT_VM0();
    __builtin_amdgcn_s_barrier();
  } else {
    issueA(0);
    dmaW(0, 0);
    WAIT_VM0();
    writeA(As[0]);
    issueA(1);
    WAIT_LGKM0();
    __builtin_amdgcn_s_barrier();
  }

  int cur = 0;
  for (int kst = 0; kst < nK; ++kst) {
    if (kst < nK - 1) {
      if (GMB == 0) dmaA(kst + 1, cur ^ 1);
      dmaW(kst + 1, cur ^ 1);
    }
    bf8_t af = *(const bf8_t*)&As[cur][swz8(w * 16 + lrow, lk)];
#pragma unroll
    for (int ct = 0; ct < 9; ++ct) {
      bf8_t bf = *(const bf8_t*)&Ws[cur][swz8(ct * 16 + lrow, lk)];
      acc[ct] = MFMA16(af, bf, acc[ct]);
    }
    if (kst < nK - 1) {
      WAIT_VM0();
      if (GMB == 1) {
        writeA(As[cur ^ 1]);
        if (kst < nK - 2) issueA(kst + 2);
        WAIT_LGKM0();
      }
      __builtin_amdgcn_s_barrier();
    }
    cur ^= 1;
  }

#pragma unroll
  for (int ct = 0; ct < 9; ++ct) {
    const int col = ct * 16 + lrow;
    if (col < N) {
      const float bb = bias[col];
#pragma unroll
      for (int r = 0; r < 4; ++r) {
        const int n = n0 + w * 16 + lk * 4 + r;
        float v = (acc[ct][r] + bb) * scale;
        if (RELU) v = fmaxf(v, 0.f);
        if (OM == 0) ((float*)out)[(size_t)n * ost + col] = v;
        else         ((u16*)out)[(size_t)n * ost + col] = f2bf(v);
      }
    }
  }
}

// ---------------------------------------------------------------------------
// emb pack: f32 [rows][128] -> bf16 into dst cols 129..256 (stride 288)
// ---------------------------------------------------------------------------
__global__ __launch_bounds__(256) void embpack_k(
    const float* __restrict__ src, u16* __restrict__ dst, int rows)
{
  int idx = blockIdx.x * 256 + threadIdx.x;
  if (idx >= rows * 128) return;
  int n = idx >> 7, c = idx & 127;
  dst[(size_t)n * 288 + 129 + c] = f2bf(src[idx]);
}

// ---------------------------------------------------------------------------
// i=0 attention: per batch b, 5 queries x 5 keys, dim 129.
// ---------------------------------------------------------------------------
__global__ __launch_bounds__(256) void attn0_k(
    const float* __restrict__ qp, const float* __restrict__ kp,
    const float* __restrict__ vp, u16* __restrict__ o0b)
{
  __shared__ float qs[4][5][SQ_], ks[4][5][SQ_], vs[4][5][SQ_];
  __shared__ float ps[4][5][8];
  const int t = threadIdx.x;
  const int bbase = blockIdx.x * 4;
  for (int idx = t; idx < 4 * 5 * SQ_; idx += 256) {
    int bl = idx / (5 * SQ_);
    int rem = idx - bl * 5 * SQ_;
    int row = rem / SQ_;
    int d = rem - row * SQ_;
    int n = (bbase + bl) * 5 + row;
    float qv = 0.f, kv = 0.f, vv = 0.f;
    if (d < QD_) { qv = qp[n * SQ_ + d]; kv = kp[n * SQ_ + d]; vv = vp[n * SQ_ + d]; }
    qs[bl][row][d] = qv; ks[bl][row][d] = kv; vs[bl][row][d] = vv;
  }
  __syncthreads();
  const int w = t >> 6, lane = t & 63;
  if (lane < 25) {
    int qq = lane / 5, kk = lane - (lane / 5) * 5;
    float s = 0.f;
    for (int c = 0; c < QD_; ++c) s += qs[w][qq][c] * ks[w][kk][c];
    ps[w][qq][kk] = s;
  }
  __syncthreads();
  if (lane < 5) {
    float m = -1e30f;
#pragma unroll
    for (int k = 0; k < 5; ++k) m = fmaxf(m, ps[w][lane][k]);
    float l = 0.f; float e[5];
#pragma unroll
    for (int k = 0; k < 5; ++k) { e[k] = __expf(ps[w][lane][k] - m); l += e[k]; }
    float inv = 1.f / l;
#pragma unroll
    for (int k = 0; k < 5; ++k) ps[w][lane][k] = e[k] * inv;
  }
  __syncthreads();
  for (int d = lane; d < 160; d += 64) {
#pragma unroll
    for (int qq = 0; qq < 5; ++qq) {
      float o = 0.f;
      if (d < QD_) {
#pragma unroll
        for (int k = 0; k < 5; ++k) o += ps[w][qq][k] * vs[w][k][d];
      }
      o0b[(size_t)((bbase + w) * 5 + qq) * 160 + d] = f2bf(o);
    }
  }
}

// ---------------------------------------------------------------------------
// i=1 MFMA flash attention (unchanged).
// ---------------------------------------------------------------------------
#define KSS 168
#define VSS 72
#define PSS 72
#define NSPLIT 4
__global__ __launch_bounds__(256) void flashm_k(
    const u16* __restrict__ qp, const u16* __restrict__ kp,
    const u16* __restrict__ vpT, float* __restrict__ oacc,
    float* __restrict__ marr, float* __restrict__ larr)
{
  __shared__ u16 ks[64 * KSS];
  __shared__ u16 vsT[VPAD * VSS];
  __shared__ u16 ps[64 * PSS];
  const int t = threadIdx.x;
  const int split = blockIdx.x & (NSPLIT - 1);
  const int q0 = (blockIdx.x >> 2) * 64;
  const int w = t >> 6, lane = t & 63;
  const int lrow = lane & 15, lk = lane >> 4;

  bf8_t qf[5];
  {
    const u16* qrow = qp + (size_t)(q0 + w * 16 + lrow) * QPAD;
#pragma unroll
    for (int kst = 0; kst < 5; ++kst)
      qf[kst] = *(const bf8_t*)(qrow + kst * 32 + lk * 8);
  }

  f4_t acc[9];
#pragma unroll
  for (int ct = 0; ct < 9; ++ct) acc[ct] = (f4_t){0.f, 0.f, 0.f, 0.f};
  float m_[4] = {-1e30f, -1e30f, -1e30f, -1e30f};
  float l_[4] = {0.f, 0.f, 0.f, 0.f};

  const int kbase = split * (B_ / NSPLIT);
  for (int tile = 0; tile < (B_ / NSPLIT) / 64; ++tile) {
    const int k0 = kbase + tile * 64;
    __syncthreads();
    for (int e = t; e < 64 * 20; e += 256) {
      int r = e / 20, c = e - r * 20;
      *(uint4*)&ks[r * KSS + c * 8] = *(const uint4*)(kp + (size_t)(k0 + r) * QPAD + c * 8);
    }
    for (int e = t; e < VPAD * 8; e += 256) {
      int r = e >> 3, c = e & 7;
      *(uint4*)&vsT[r * VSS + c * 8] = *(const uint4*)(vpT + (size_t)r * B_ + k0 + c * 8);
    }
    __syncthreads();

    f4_t s[4];
#pragma unroll
    for (int ct = 0; ct < 4; ++ct) s[ct] = (f4_t){0.f, 0.f, 0.f, 0.f};
#pragma unroll
    for (int kst = 0; kst < 5; ++kst) {
#pragma unroll
      for (int ct = 0; ct < 4; ++ct) {
        bf8_t b = *(const bf8_t*)&ks[(ct * 16 + lrow) * KSS + kst * 32 + lk * 8];
        s[ct] = MFMA16(qf[kst], b, s[ct]);
      }
    }

    float pm[4];
#pragma unroll
    for (int r = 0; r < 4; ++r) {
      pm[r] = fmaxf(fmaxf(s[0][r], s[1][r]), fmaxf(s[2][r], s[3][r]));
#pragma unroll
      for (int mk = 1; mk <= 8; mk <<= 1) pm[r] = fmaxf(pm[r], __shfl_xor(pm[r], mk));
    }
    float cf[4], rs[4];
#pragma unroll
    for (int r = 0; r < 4; ++r) {
      float mn = fmaxf(m_[r], pm[r]);
      cf[r] = __expf(m_[r] - mn);
      m_[r] = mn;
      rs[r] = 0.f;
    }
#pragma unroll
    for (int ct = 0; ct < 4; ++ct) {
#pragma unroll
      for (int r = 0; r < 4; ++r) {
        float p = __expf(s[ct][r] - m_[r]);
        ps[(w * 16 + lk * 4 + r) * PSS + ct * 16 + lrow] = f2bf(p);
        rs[r] += p;
      }
    }
#pragma unroll
    for (int r = 0; r < 4; ++r) {
#pragma unroll
      for (int mk = 1; mk <= 8; mk <<= 1) rs[r] += __shfl_xor(rs[r], mk);
      l_[r] = l_[r] * cf[r] + rs[r];
    }
#pragma unroll
    for (int ct = 0; ct < 9; ++ct) {
#pragma unroll
      for (int r = 0; r < 4; ++r) acc[ct][r] *= cf[r];
    }
    __syncthreads();

#pragma unroll
    for (int kst = 0; kst < 2; ++kst) {
      bf8_t a = *(const bf8_t*)&ps[(w * 16 + lrow) * PSS + kst * 32 + lk * 8];
#pragma unroll
      for (int ct = 0; ct < 9; ++ct) {
        bf8_t b = *(const bf8_t*)&vsT[(ct * 16 + lrow) * VSS + kst * 32 + lk * 8];
        acc[ct] = MFMA16(a, b, acc[ct]);
      }
    }
  }

#pragma unroll
  for (int ct = 0; ct < 9; ++ct) {
    const int col = ct * 16 + lrow;
    if (col < SQ_) {
#pragma unroll
      for (int r = 0; r < 4; ++r)
        oacc[((size_t)split * B_ + q0 + w * 16 + lk * 4 + r) * SQ_ + col] = acc[ct][r];
    }
  }
  if (lrow == 0) {
#pragma unroll
    for (int r = 0; r < 4; ++r) {
      size_t i = (size_t)split * B_ + q0 + w * 16 + lk * 4 + r;
      marr[i] = m_[r];
      larr[i] = l_[r];
    }
  }
}

// ---------------------------------------------------------------------------
// combine splits -> o1b bf16 [8192][160] (pads zeroed)
// ---------------------------------------------------------------------------
__global__ __launch_bounds__(256) void combine_k(
    const float* __restrict__ oacc, const float* __restrict__ marr,
    const float* __restrict__ larr, u16* __restrict__ o1b)
{
  int idx = blockIdx.x * 256 + threadIdx.x;
  if (idx >= B_ * 160) return;
  int n = idx / 160, d = idx - n * 160;
  float v = 0.f;
  if (d < QD_) {
    float m = -1e30f;
#pragma unroll
    for (int s = 0; s < NSPLIT; ++s) m = fmaxf(m, marr[s * B_ + n]);
    float l = 0.f, o = 0.f;
#pragma unroll
    for (int s = 0; s < NSPLIT; ++s) {
      float e = __expf(marr[s * B_ + n] - m);
      l += larr[s * B_ + n] * e;
      o += oacc[((size_t)s * B_ + n) * SQ_ + d] * e;
    }
    v = o / l;
  }
  o1b[idx] = f2bf(v);
}

// ---------------------------------------------------------------------------
extern "C" void kernel_launch(void* const* d_in, const int* in_sizes, int n_in,
                              void* d_out, int out_size, void* d_ws, size_t ws_size,
                              hipStream_t stream)
{
  const float* emb0 = (const float*)d_in[0];
  const float* ef0  = (const float*)d_in[1];
  const float* td0  = (const float*)d_in[2];
  const float* emb1 = (const float*)d_in[3];
  const float* ef1  = (const float*)d_in[4];
  const float* td1  = (const float*)d_in[5];
  const float* emb2 = (const float*)d_in[6];
  const float* Wq = (const float*)d_in[7];  const float* bq = (const float*)d_in[8];
  const float* Wk = (const float*)d_in[9];  const float* bk = (const float*)d_in[10];
  const float* Wv = (const float*)d_in[11]; const float* bv = (const float*)d_in[12];
  const float* Wo = (const float*)d_in[13]; const float* bo = (const float*)d_in[14];
  const float* W1 = (const float*)d_in[15]; const float* b1 = (const float*)d_in[16];
  const float* W2 = (const float*)d_in[17]; const float* b2 = (const float*)d_in[18];
  float* out = (float*)d_out;

  char* ws = (char*)d_ws;
  u16* wb   = (u16*)ws;
  u16* wkv  = wb;
  u16* wq_b = wb + 377856;
  u16* wo_b = wb + 400896;
  u16* w1_b = wb + 423936;
  u16* w2_b = wb + 465408;
  float* kp0 = (float*)(ws + 1048576);    // [40960][132] f32
  float* vp0 = (float*)(ws + 22675456);
  float* qp0 = (float*)(ws + 44302336);
  u16*   o0b = (u16*)(ws + 65929216);     // [40960][160] bf16
  u16*   cat0= (u16*)(ws + 1048576);      // [40960][288] bf16 (overlays kp0/vp0)
  u16*   h0  = (u16*)(ws + 24641536);     // [40960][128] bf16
  u16*   qp1b = (u16*)(ws + 44302336);    // [8192][160]
  u16*   kp1b = (u16*)(ws + 46923776);
  u16*   vp1T = (u16*)(ws + 49545216);    // [144][8192]
  u16*   o1b  = (u16*)(ws + 51904512);    // [8192][160]
  float* marr = (float*)(ws + 54525952);
  float* larr = (float*)(ws + 54657024);
  u16*   cat1 = (u16*)(ws + 54788096);    // [8192][288]
  u16*   h1   = (u16*)(ws + 59506688);    // [8192][128]
  float* oacc = (float*)(ws + 79036416);  // [4][8192][132]

  const float scale = 0.08804509063256238f;  // 1/sqrt(129)

  convw_k<<<1890, 256, 0, stream>>>(Wq, Wk, Wv, Wo, W1, W2, wb);

  // ---- i = 0 -------------------------------------------------------------
  kvmm_k<0, 0><<<BK_ / 64, 256, 0, stream>>>(
      emb0, ef0, td0, wkv, bk, kp0, SQ_, bv, vp0, SQ_);
  mmb_k<1, false, 0><<<BK_ / 64, 256, 0, stream>>>(
      5, emb1, 0, td1, wq_b, bq, scale, qp0, SQ_, QD_);
  attn0_k<<<B_ / 4, 256, 0, stream>>>(qp0, kp0, vp0, o0b);
  hipMemsetAsync(cat0, 0, 23592960, stream);
  embpack_k<<<(BK_ * 128 + 255) / 256, 256, 0, stream>>>(emb1, cat0, BK_);
  mmb_k<0, false, 1><<<BK_ / 64, 256, 0, stream>>>(
      5, o0b, 160, nullptr, wo_b, bo, 1.f, cat0, 288, QD_);
  mmb_k<0, true, 1><<<BK_ / 64, 256, 0, stream>>>(
      9, cat0, 288, nullptr, w1_b, b1, 1.f, h0, 128, 128);
  mmb_k<0, false, 0><<<BK_ / 64, 256, 0, stream>>>(
      4, h0, 128, nullptr, w2_b, b2, 1.f, out, 128, 128);

  // ---- i = 1 -------------------------------------------------------------
  hipMemsetAsync(qp1b, 0, 2621440, stream);
  hipMemsetAsync(kp1b, 0, 2621440, stream);
  hipMemsetAsync(vp1T, 0, 2359296, stream);
  kvmm_k<1, 2><<<B_ / 64, 256, 0, stream>>>(
      emb1, ef1, td1, wkv, bk, kp1b, QPAD, bv, vp1T, B_);
  mmb_k<1, false, 1><<<B_ / 64, 256, 0, stream>>>(
      5, emb2, 0, nullptr, wq_b, bq, scale, qp1b, QPAD, QD_);
  flashm_k<<<(B_ / 64) * NSPLIT, 256, 0, stream>>>(qp1b, kp1b, vp1T, oacc, marr, larr);
  combine_k<<<(B_ * 160 + 255) / 256, 256, 0, stream>>>(oacc, marr, larr, o1b);
  hipMemsetAsync(cat1, 0, 4718592, stream);
  embpack_k<<<(B_ * 128 + 255) / 256, 256, 0, stream>>>(emb2, cat1, B_);
  mmb_k<0, false, 1><<<B_ / 64, 256, 0, stream>>>(
      5, o1b, 160, nullptr, wo_b, bo, 1.f, cat1, 288, QD_);
  mmb_k<0, true, 1><<<B_ / 64, 256, 0, stream>>>(
      9, cat1, 288, nullptr, w1_b, b1, 1.f, h1, 128, 128);
  mmb_k<0, false, 0><<<B_ / 64, 256, 0, stream>>>(
      4, h1, 128, nullptr, w2_b, b2, 1.f, out + (size_t)BK_ * D_, 128, 128);
}